// Round 6
// baseline (115.504 us; speedup 1.0000x reference)
//
#include <hip/hip_runtime.h>

// Network24: out = sigmoid( m0*h0 + m1*h1 + (m2*h0)*(m3*h1) + bias3 )
//   h_j = sigmoid( tw[j][0]*x0 + tw[j][1]*x1 + b_j )        (powers == 1.0)
//
// R5 post-mortem: all one-shot-wave variants cluster at ~40 us regardless of
// VALU load or coalescing -> limit is wave lifecycle (one latency exposure per
// wave, 32768 waves of churn), not any pipe. fillBuffer hits 6.4 TB/s with
// persistent grid-stride waves on the same memory system.
// Fix: persistent waves (8192), 4 tiles/wave, register double-buffer so the
// next tile's loads are in flight while the current tile computes/stores.

typedef float vfloat4 __attribute__((ext_vector_type(4)));
typedef float vfloat2 __attribute__((ext_vector_type(2)));

__device__ __forceinline__ float sigmoid_fast(float z) {
    float t = __expf(-z);                      // v_mul + v_exp_f32
    return __builtin_amdgcn_rcpf(1.0f + t);    // v_add + v_rcp_f32 (~1 ulp)
}
__device__ __forceinline__ float sigmoid_exact(float z) {
    return 1.0f / (1.0f + expf(-z));
}
__device__ __forceinline__ float pw(float x, float p) {
    return (p == 1.0f) ? x : __powf(x, p);
}

__global__ __launch_bounds__(256) void net24_kernel(
    const float* __restrict__ x,        // (n, 2) row-major
    float* __restrict__ out,            // (n,)
    const float* __restrict__ fc1_tw,   // (2,2,3) -> use [j,k,0] = j*6+k*3
    const float* __restrict__ fc1_power,// (2,2)
    const float* __restrict__ fc1_bias, // (2,)
    const float* __restrict__ m4_tw,    // (4,3) -> use [i,0] = i*3
    const float* __restrict__ m4_power, // (4,)
    const float* __restrict__ m4_bias3, // (1,)
    int n)                              // rows
{
    const float tw00 = fc1_tw[0], tw01 = fc1_tw[3], tw10 = fc1_tw[6], tw11 = fc1_tw[9];
    const float p00 = fc1_power[0], p01 = fc1_power[1], p10 = fc1_power[2], p11 = fc1_power[3];
    const float b0 = fc1_bias[0], b1 = fc1_bias[1];
    const float m0 = m4_tw[0], m1 = m4_tw[3], m2 = m4_tw[6], m3 = m4_tw[9];
    const float q0 = m4_power[0], q1 = m4_power[1], q2 = m4_power[2], q3 = m4_power[3];
    const float bias3 = m4_bias3[0];

    const bool all_pow1 = (p00 == 1.0f) & (p01 == 1.0f) & (p10 == 1.0f) & (p11 == 1.0f) &
                          (q0 == 1.0f) & (q1 == 1.0f) & (q2 == 1.0f) & (q3 == 1.0f);

    auto eval_fast = [&](float x0, float x1) -> float {
        float h0 = sigmoid_fast(fmaf(tw00, x0, fmaf(tw01, x1, b0)));
        float h1 = sigmoid_fast(fmaf(tw10, x0, fmaf(tw11, x1, b1)));
        float s  = fmaf(m0, h0, fmaf(m1, h1, bias3));
        s = fmaf(m2 * h0, m3 * h1, s);
        return sigmoid_fast(s);
    };
    auto eval_gen = [&](float x0, float x1) -> float {
        float h0 = sigmoid_exact(fmaf(tw00, pw(x0, p00), fmaf(tw01, pw(x1, p01), b0)));
        float h1 = sigmoid_exact(fmaf(tw10, pw(x0, p10), fmaf(tw11, pw(x1, p11), b1)));
        float s  = fmaf(m0, pw(h0, q0), fmaf(m1, pw(h1, q1), bias3));
        s = fmaf(m2 * pw(h0, q2), m3 * pw(h1, q3), s);
        return sigmoid_exact(s);
    };

    const int gid   = blockIdx.x * blockDim.x + threadIdx.x;
    const int wave  = gid >> 6;
    const int lane  = gid & 63;
    const int nwaves = (gridDim.x * blockDim.x) >> 6;       // total persistent waves
    const long long ntiles = ((long long)n + 255) >> 8;     // 256 rows per tile

    if (all_pow1 && (n & 255) == 0) {
        // Fast path: all tiles full. Persistent loop with register double-buffer:
        // tile t+nwaves' loads are issued BEFORE tile t's results are consumed.
        long long t = wave;
        if (t >= ntiles) return;

        const vfloat4* xv0 = (const vfloat4*)(x + (t << 9));
        vfloat4 a0 = xv0[lane];
        vfloat4 b0 = xv0[64 + lane];

        while (true) {
            const long long tn = t + nwaves;
            vfloat4 a1, b1;
            const bool more = tn < ntiles;
            if (more) {
                const vfloat4* xv1 = (const vfloat4*)(x + (tn << 9));
                a1 = xv1[lane];            // in flight during compute below
                b1 = xv1[64 + lane];
            }

            vfloat2 ra, rb;
            ra.x = eval_fast(a0.x, a0.y);
            ra.y = eval_fast(a0.z, a0.w);
            rb.x = eval_fast(b0.x, b0.y);
            rb.y = eval_fast(b0.z, b0.w);
            float* o = out + (t << 8);
            __builtin_nontemporal_store(ra, (vfloat2*)(o + 2 * lane));
            __builtin_nontemporal_store(rb, (vfloat2*)(o + 128 + 2 * lane));

            if (!more) break;
            t = tn; a0 = a1; b0 = b1;
        }
    } else {
        // Generic path: arbitrary powers / ragged n.
        for (long long t = wave; t < ntiles; t += nwaves) {
            const long long rowbase = t << 8;
            for (long long r = rowbase + lane; r < rowbase + 256 && r < n; r += 64) {
                out[r] = eval_gen(x[r * 2], x[r * 2 + 1]);
            }
        }
    }
}

extern "C" void kernel_launch(void* const* d_in, const int* in_sizes, int n_in,
                              void* d_out, int out_size, void* d_ws, size_t ws_size,
                              hipStream_t stream) {
    const float* x         = (const float*)d_in[0];
    const float* fc1_tw    = (const float*)d_in[1];
    const float* fc1_power = (const float*)d_in[2];
    const float* fc1_bias  = (const float*)d_in[3];
    const float* m4_tw     = (const float*)d_in[4];
    const float* m4_power  = (const float*)d_in[5];
    const float* m4_bias3  = (const float*)d_in[6];
    float* out = (float*)d_out;

    const int n = out_size;                               // B rows
    const long long ntiles = ((long long)n + 255) / 256;  // 256 rows per wave-tile
    // Persistent grid: 8 blocks/CU (VGPR<=32 -> full 32 waves/CU occupancy),
    // capped so no wave is workless.
    long long blocks = 2048;
    const long long waves_needed = ntiles;
    const long long max_blocks = (waves_needed + 3) / 4;  // 4 waves per block
    if (blocks > max_blocks) blocks = max_blocks;
    if (blocks < 1) blocks = 1;

    net24_kernel<<<(int)blocks, 256, 0, stream>>>(x, out, fc1_tw, fc1_power, fc1_bias,
                                                  m4_tw, m4_power, m4_bias3, n);
}

// Round 7
// 108.905 us; speedup vs baseline: 1.0606x; 1.0606x over previous
//
#include <hip/hip_runtime.h>

// Network24: out = sigmoid( m0*h0 + m1*h1 + (m2*h0)*(m3*h1) + bias3 )
//   h_j = sigmoid( tw[j][0]*x0 + tw[j][1]*x1 + b_j )        (powers == 1.0)
//
// R6 post-mortem: persistent+dbuf+NT regressed ~8 us vs R5. NT stores bypass
// L2 write aggregation -> suspected cause. R7 = R6 with PLAIN stores only
// (isolates NT effect; persistence vs one-shot resolved by R7-vs-R5 delta).

typedef float vfloat4 __attribute__((ext_vector_type(4)));
typedef float vfloat2 __attribute__((ext_vector_type(2)));

__device__ __forceinline__ float sigmoid_fast(float z) {
    float t = __expf(-z);                      // v_mul + v_exp_f32
    return __builtin_amdgcn_rcpf(1.0f + t);    // v_add + v_rcp_f32 (~1 ulp)
}
__device__ __forceinline__ float sigmoid_exact(float z) {
    return 1.0f / (1.0f + expf(-z));
}
__device__ __forceinline__ float pw(float x, float p) {
    return (p == 1.0f) ? x : __powf(x, p);
}

__global__ __launch_bounds__(256) void net24_kernel(
    const float* __restrict__ x,        // (n, 2) row-major
    float* __restrict__ out,            // (n,)
    const float* __restrict__ fc1_tw,   // (2,2,3) -> use [j,k,0] = j*6+k*3
    const float* __restrict__ fc1_power,// (2,2)
    const float* __restrict__ fc1_bias, // (2,)
    const float* __restrict__ m4_tw,    // (4,3) -> use [i,0] = i*3
    const float* __restrict__ m4_power, // (4,)
    const float* __restrict__ m4_bias3, // (1,)
    int n)                              // rows
{
    const float tw00 = fc1_tw[0], tw01 = fc1_tw[3], tw10 = fc1_tw[6], tw11 = fc1_tw[9];
    const float p00 = fc1_power[0], p01 = fc1_power[1], p10 = fc1_power[2], p11 = fc1_power[3];
    const float b0 = fc1_bias[0], b1 = fc1_bias[1];
    const float m0 = m4_tw[0], m1 = m4_tw[3], m2 = m4_tw[6], m3 = m4_tw[9];
    const float q0 = m4_power[0], q1 = m4_power[1], q2 = m4_power[2], q3 = m4_power[3];
    const float bias3 = m4_bias3[0];

    const bool all_pow1 = (p00 == 1.0f) & (p01 == 1.0f) & (p10 == 1.0f) & (p11 == 1.0f) &
                          (q0 == 1.0f) & (q1 == 1.0f) & (q2 == 1.0f) & (q3 == 1.0f);

    auto eval_fast = [&](float x0, float x1) -> float {
        float h0 = sigmoid_fast(fmaf(tw00, x0, fmaf(tw01, x1, b0)));
        float h1 = sigmoid_fast(fmaf(tw10, x0, fmaf(tw11, x1, b1)));
        float s  = fmaf(m0, h0, fmaf(m1, h1, bias3));
        s = fmaf(m2 * h0, m3 * h1, s);
        return sigmoid_fast(s);
    };
    auto eval_gen = [&](float x0, float x1) -> float {
        float h0 = sigmoid_exact(fmaf(tw00, pw(x0, p00), fmaf(tw01, pw(x1, p01), b0)));
        float h1 = sigmoid_exact(fmaf(tw10, pw(x0, p10), fmaf(tw11, pw(x1, p11), b1)));
        float s  = fmaf(m0, pw(h0, q0), fmaf(m1, pw(h1, q1), bias3));
        s = fmaf(m2 * pw(h0, q2), m3 * pw(h1, q3), s);
        return sigmoid_exact(s);
    };

    const int gid   = blockIdx.x * blockDim.x + threadIdx.x;
    const int wave  = gid >> 6;
    const int lane  = gid & 63;
    const int nwaves = (gridDim.x * blockDim.x) >> 6;       // total persistent waves
    const long long ntiles = ((long long)n + 255) >> 8;     // 256 rows per tile

    if (all_pow1 && (n & 255) == 0) {
        // Persistent loop, register double-buffer: tile t+nwaves' loads are in
        // flight while tile t computes and stores.
        long long t = wave;
        if (t >= ntiles) return;

        const vfloat4* xv0 = (const vfloat4*)(x + (t << 9));
        vfloat4 a0 = xv0[lane];
        vfloat4 b0 = xv0[64 + lane];

        while (true) {
            const long long tn = t + nwaves;
            vfloat4 a1, b1;
            const bool more = tn < ntiles;
            if (more) {
                const vfloat4* xv1 = (const vfloat4*)(x + (tn << 9));
                a1 = xv1[lane];
                b1 = xv1[64 + lane];
            }

            vfloat2 ra, rb;
            ra.x = eval_fast(a0.x, a0.y);
            ra.y = eval_fast(a0.z, a0.w);
            rb.x = eval_fast(b0.x, b0.y);
            rb.y = eval_fast(b0.z, b0.w);
            float* o = out + (t << 8);
            *(vfloat2*)(o + 2 * lane)       = ra;   // plain stores: keep L2 write path
            *(vfloat2*)(o + 128 + 2 * lane) = rb;

            if (!more) break;
            t = tn; a0 = a1; b0 = b1;
        }
    } else {
        // Generic path: arbitrary powers / ragged n.
        for (long long t = wave; t < ntiles; t += nwaves) {
            const long long rowbase = t << 8;
            for (long long r = rowbase + lane; r < rowbase + 256 && r < n; r += 64) {
                out[r] = eval_gen(x[r * 2], x[r * 2 + 1]);
            }
        }
    }
}

extern "C" void kernel_launch(void* const* d_in, const int* in_sizes, int n_in,
                              void* d_out, int out_size, void* d_ws, size_t ws_size,
                              hipStream_t stream) {
    const float* x         = (const float*)d_in[0];
    const float* fc1_tw    = (const float*)d_in[1];
    const float* fc1_power = (const float*)d_in[2];
    const float* fc1_bias  = (const float*)d_in[3];
    const float* m4_tw     = (const float*)d_in[4];
    const float* m4_power  = (const float*)d_in[5];
    const float* m4_bias3  = (const float*)d_in[6];
    float* out = (float*)d_out;

    const int n = out_size;                               // B rows
    const long long ntiles = ((long long)n + 255) / 256;  // 256 rows per wave-tile
    long long blocks = 2048;                              // 8 blocks/CU persistent
    const long long max_blocks = (ntiles + 3) / 4;        // 4 waves per block
    if (blocks > max_blocks) blocks = max_blocks;
    if (blocks < 1) blocks = 1;

    net24_kernel<<<(int)blocks, 256, 0, stream>>>(x, out, fc1_tw, fc1_power, fc1_bias,
                                                  m4_tw, m4_power, m4_bias3, n);
}